// Round 14
// baseline (176.695 us; speedup 1.0000x reference)
//
#include <hip/hip_runtime.h>
#include <math.h>
#include <float.h>

// DeepSeek V3 router, round 14.
// Root cause of the 28% plateau (R9/R11/R13 identical): per-wave in-order
// vmcnt FIFO mixes slow HBM X-loads with fast L2 B-loads -> every counted
// B-wait transitively drains X; all waves stall at the same phase point.
// Fix: producer/consumer FIFO decoupling.
//  - X staged fp32 via global_load_lds by WAVE 0 ONLY (pre-swizzled global
//    source, linear LDS dest; reads 2-way max). Consumers' FIFOs carry only
//    L2 B-loads (~200cy). Producer uses counted vmcnt(16), never 0 mid-loop.
//  - fp32->2-plane fp16 conversion moved to consumers (VALU co-issues).
//  - ONE barrier per K32 step (R13 had 8 per K64). Triple-buffered X tile.
//  - B half-step reg buffers reloaded right after consumption (1-step slack).
// Numerics bitwise-identical to validated R7-R13: per-acc order pass1 a0*b0;
// RB*=S5; pass2 (a1*=S6)*b0s; a0*=S5; pass3 a0s*b3; logit = acc/256.

#define TDIM 8192
#define DDIM 7168
#define EDIM 256
#define KT   (DDIM / 32)   // 224 k-tiles of 32

typedef _Float16 h8 __attribute__((ext_vector_type(8)));
typedef float f16v __attribute__((ext_vector_type(16)));

typedef const __attribute__((address_space(1))) void* gas_t;
typedef __attribute__((address_space(3))) void* las_t;

// ---------------- K1: W -> 32x32x16-fragment-packed fp16 planes ------------
// (validated R9-R13) Offset(halfs) = (((p*8+cf)*KT+ktl)*2+kf)*512 + lane*8,
// lane = (e&31) + 32*((k>>3)&1).
__global__ __launch_bounds__(256)
void convert_w(const float* __restrict__ W, _Float16* __restrict__ Bp)
{
    __shared__ _Float16 l0[64][80];
    __shared__ _Float16 l1[64][80];
    const int t = threadIdx.x;
    const int kt = blockIdx.x * 64;
    const int et = blockIdx.y * 64;
#pragma unroll
    for (int i = 0; i < 16; ++i) {
        const int kr = (t >> 6) * 16 + i;
        const int ec = t & 63;
        const float w = W[(size_t)(kt + kr) * EDIM + et + ec] * 256.f;
        const _Float16 h0 = (_Float16)w;
        const _Float16 h1 = (_Float16)((w - (float)h0) * 32.f);
        l0[ec][kr] = h0;
        l1[ec][kr] = h1;
    }
    __syncthreads();
#pragma unroll
    for (int j = 0; j < 2; ++j) {
        const int er = t >> 2;
        const int kc = ((t & 3) + 4 * j) * 8;
        const int e  = et + er;
        const int k  = kt + kc;
        const int cf   = e >> 5;
        const int lane = (e & 31) + 32 * ((k >> 3) & 1);
        const int kf   = (k >> 4) & 1;
        const int ktl  = k >> 5;
        const uint4 v0 = *(const uint4*)&l0[er][kc];
        const uint4 v1 = *(const uint4*)&l1[er][kc];
        const size_t o0 = (((size_t)(0 * 8 + cf) * KT + ktl) * 2 + kf) * 512 + lane * 8;
        const size_t o1 = (((size_t)(1 * 8 + cf) * KT + ktl) * 2 + kf) * 512 + lane * 8;
        *(uint4*)&Bp[o0] = v0;
        *(uint4*)&Bp[o1] = v1;
    }
}

// ---- K2: producer/consumer split-fp16 GEMM (X DMA by wave0, B from L2) ----
__global__ __launch_bounds__(256, 2)
void gemm_mfma(const float* __restrict__ X,
               const _Float16* __restrict__ Bp,
               float* __restrict__ P,
               int splitK, int kLen)
{
    __shared__ float sX[3][64][32];   // fp32 X tiles, 3 x 8 KB

    const int t    = threadIdx.x;
    const int lane = t & 63;
    const int w    = t >> 6;                // wave -> n-quadrant w*64

    const int bid  = blockIdx.x;
    const int ks   = (bid & 7) % splitK;
    const int mb   = (bid >> 3) * (8 / splitK) + (bid & 7) / splitK;
    const int m0   = mb * 64;
    const int kbeg = ks * kLen;
    const int nst  = kLen >> 5;             // 56 K32 steps
    const int k16b = kbeg >> 4;

    f16v acc[2][2];
#pragma unroll
    for (int m = 0; m < 2; ++m)
#pragma unroll
        for (int n = 0; n < 2; ++n) acc[m][n] = (f16v)0.f;

    // producer source: lane l -> row l>>3, source granule (l&7)^((l>>3)&7)
    const float* xsrc = X + (size_t)(m0 + (lane >> 3)) * DDIM + kbeg
                          + (((lane & 7) ^ ((lane >> 3) & 7)) << 2);
    const _Float16* bb = Bp + lane * 8;

    const _Float16 S5 = (_Float16)0.03125f;     // 2^-5
    const _Float16 S6 = (_Float16)0.015625f;    // 2^-6

#define XSTAGE(BUF, S)                                                        \
    {                                                                         \
        _Pragma("unroll")                                                     \
        for (int i = 0; i < 8; ++i)                                           \
            __builtin_amdgcn_global_load_lds(                                 \
                (gas_t)(xsrc + (size_t)i * 8 * DDIM + (S) * 32),              \
                (las_t)&sX[BUF][i * 8][0], 16, 0, 0);                         \
    }

#define BLOADH(RB, S, KF)                                                     \
    {                                                                         \
        _Pragma("unroll")                                                     \
        for (int p = 0; p < 2; ++p)                                           \
        _Pragma("unroll")                                                     \
        for (int n = 0; n < 2; ++n)                                           \
            RB[n][p] = *(const h8*)(bb +                                      \
                ((size_t)(p * 8 + w * 2 + n) * (2 * KT) +                     \
                 k16b + 2 * (S) + (KF)) * 512);                               \
    }

#define AREADCONV(C)                                                          \
    {                                                                         \
        _Pragma("unroll")                                                     \
        for (int m = 0; m < 2; ++m)                                           \
        _Pragma("unroll")                                                     \
        for (int kf = 0; kf < 2; ++kf) {                                      \
            const int rr = m * 32 + (lane & 31);                              \
            const int g0 = kf * 4 + (lane >> 5) * 2;                          \
            const float4 u0 = *(const float4*)&sX[C][rr][(g0 ^ (rr & 7)) << 2];       \
            const float4 u1 = *(const float4*)&sX[C][rr][((g0 + 1) ^ (rr & 7)) << 2]; \
            const float xv[8] = {u0.x, u0.y, u0.z, u0.w,                      \
                                 u1.x, u1.y, u1.z, u1.w};                     \
            h8 p0, p1;                                                        \
            _Pragma("unroll")                                                 \
            for (int q = 0; q < 8; ++q) {                                     \
                const _Float16 h0 = (_Float16)xv[q];                          \
                p0[q] = h0;                                                   \
                p1[q] = (_Float16)((xv[q] - (float)h0) * 2048.f);             \
            }                                                                 \
            a0[m][kf] = p0;                                                   \
            a1[m][kf] = p1;                                                   \
        }                                                                     \
    }

#define MFMAK(KF, RB)                                                         \
    {                                                                         \
        __builtin_amdgcn_s_setprio(1);                                        \
        _Pragma("unroll")                                                     \
        for (int m = 0; m < 2; ++m)                                           \
        _Pragma("unroll")                                                     \
        for (int n = 0; n < 2; ++n)                                           \
            acc[m][n] = __builtin_amdgcn_mfma_f32_32x32x16_f16(               \
                a0[m][KF], RB[n][0], acc[m][n], 0, 0, 0);                     \
        _Pragma("unroll")                                                     \
        for (int n = 0; n < 2; ++n)                                           \
        _Pragma("unroll")                                                     \
        for (int q = 0; q < 8; ++q) RB[n][0][q] *= S5;                        \
        _Pragma("unroll")                                                     \
        for (int m = 0; m < 2; ++m)                                           \
        _Pragma("unroll")                                                     \
        for (int q = 0; q < 8; ++q) a1[m][KF][q] *= S6;                       \
        _Pragma("unroll")                                                     \
        for (int m = 0; m < 2; ++m)                                           \
        _Pragma("unroll")                                                     \
        for (int n = 0; n < 2; ++n)                                           \
            acc[m][n] = __builtin_amdgcn_mfma_f32_32x32x16_f16(               \
                a1[m][KF], RB[n][0], acc[m][n], 0, 0, 0);                     \
        _Pragma("unroll")                                                     \
        for (int m = 0; m < 2; ++m)                                           \
        _Pragma("unroll")                                                     \
        for (int q = 0; q < 8; ++q) a0[m][KF][q] *= S5;                       \
        _Pragma("unroll")                                                     \
        for (int m = 0; m < 2; ++m)                                           \
        _Pragma("unroll")                                                     \
        for (int n = 0; n < 2; ++n)                                           \
            acc[m][n] = __builtin_amdgcn_mfma_f32_32x32x16_f16(               \
                a0[m][KF], RB[n][1], acc[m][n], 0, 0, 0);                     \
        __builtin_amdgcn_s_setprio(0);                                        \
    }

    h8 bA[2][2], bB[2][2];

    // ---- prologue: X(0)->buf0, X(1)->buf1 (DMA); B(step0) halves ----
    if (w == 0) { XSTAGE(0, 0); XSTAGE(1, 1); }
    BLOADH(bA, 0, 0);
    BLOADH(bB, 0, 1);
    if (w == 0) {
        // X(0) complete; newer entries (X(1)=8, bA=4, bB=4) stay in flight
        asm volatile("s_waitcnt vmcnt(16)" ::: "memory");
    }
    __builtin_amdgcn_s_barrier();

    int c0 = 0, c1 = 1, c2 = 2;
    for (int s = 0; s < nst; ++s) {
        h8 a0[2][2], a1[2][2];
        AREADCONV(c0);

        MFMAK(0, bA);
        if (s + 1 < nst) BLOADH(bA, s + 1, 0);
        MFMAK(1, bB);
        if (s + 1 < nst) BLOADH(bB, s + 1, 1);

        if (w == 0) {
            if (s + 2 < nst) {
                XSTAGE(c2, s + 2);
                // X(s+1) complete; 16 newer (bA,bB,X(s+2)) stay in flight
                asm volatile("s_waitcnt vmcnt(16)" ::: "memory");
            } else if (s + 1 < nst) {
                asm volatile("s_waitcnt vmcnt(8)" ::: "memory");
            }
        }
        __builtin_amdgcn_s_barrier();

        const int tmp = c0; c0 = c1; c1 = c2; c2 = tmp;
    }

    // epilogue: logit = acc/256; C/D col=lane&31, row=(r&3)+8*(r>>2)+4*(lane>>5)
    const float s0 = 1.f / 256.f;
#pragma unroll
    for (int m = 0; m < 2; ++m)
#pragma unroll
        for (int n = 0; n < 2; ++n)
#pragma unroll
            for (int r = 0; r < 16; ++r) {
                const int row = (r & 3) + 8 * (r >> 2) + 4 * (lane >> 5);
                const int gr  = m0 + m * 32 + row;
                const int gc  = w * 64 + n * 32 + (lane & 31);
                P[((size_t)ks * TDIM + gr) * EDIM + gc] = acc[m][n][r] * s0;
            }
}

// ---------------- K3: reduce + sigmoid + grouped top-k route ----------------
__global__ __launch_bounds__(256, 4)
void route_kernel(const float* __restrict__ P,
                  const float* __restrict__ B,
                  float* __restrict__ out,
                  int splitK)
{
    const int t    = threadIdx.x;
    const int lane = t & 63;
    const int wid  = t >> 6;
    const int tok0 = blockIdx.x * 32 + wid * 8;

    const float4 bv4 = *(const float4*)&B[lane * 4];
    const float bb[4] = {bv4.x, bv4.y, bv4.z, bv4.w};
    const int g = lane >> 3;

#pragma unroll
    for (int i = 0; i < 8; ++i) {
        const int tok = tok0 + i;
        float a[4] = {0.f, 0.f, 0.f, 0.f};
        for (int ksl = 0; ksl < splitK; ++ksl) {
            const float4 pv =
                *(const float4*)&P[((size_t)ksl * TDIM + tok) * EDIM + lane * 4];
            a[0] += pv.x; a[1] += pv.y; a[2] += pv.z; a[3] += pv.w;
        }
        float v[4], s[4];
#pragma unroll
        for (int jq = 0; jq < 4; ++jq) {
            v[jq] = 1.f / (1.f + expf(-a[jq]));
            s[jq] = v[jq] + bb[jq];
        }
        float t1 = s[0], t2 = -FLT_MAX;
#pragma unroll
        for (int jq = 1; jq < 4; ++jq) {
            if (s[jq] > t1) { t2 = t1; t1 = s[jq]; }
            else if (s[jq] > t2) t2 = s[jq];
        }
#pragma unroll
        for (int d = 1; d < 8; d <<= 1) {
            float o1 = __shfl_xor(t1, d);
            float o2 = __shfl_xor(t2, d);
            float n1 = fmaxf(t1, o1);
            float n2 = fmaxf(fminf(t1, o1), fmaxf(t2, o2));
            t1 = n1; t2 = n2;
        }
        const float gsc = t1 + t2;
        float gs[8];
#pragma unroll
        for (int q = 0; q < 8; ++q) gs[q] = __shfl(gsc, q * 8);
        int gmask = 0;
#pragma unroll
        for (int it = 0; it < 4; ++it) {
            float bvv = -FLT_MAX; int bg = 0;
#pragma unroll
            for (int q = 0; q < 8; ++q) {
                const bool avail = ((gmask >> q) & 1) == 0;
                if (avail && gs[q] > bvv) { bvv = gs[q]; bg = q; }
            }
            gmask |= (1 << bg);
        }
        if (((gmask >> g) & 1) == 0) { s[0] = 0.f; s[1] = 0.f; s[2] = 0.f; s[3] = 0.f; }

        float wk[8]; int ik[8]; float wsum = 0.f;
#pragma unroll
        for (int it = 0; it < 8; ++it) {
            float bvv = s[0]; int bi = lane * 4; float bs = v[0];
#pragma unroll
            for (int jq = 1; jq < 4; ++jq)
                if (s[jq] > bvv) { bvv = s[jq]; bi = lane * 4 + jq; bs = v[jq]; }
#pragma unroll
            for (int d = 1; d < 64; d <<= 1) {
                float ov = __shfl_xor(bvv, d);
                int   oi = __shfl_xor(bi, d);
                float os = __shfl_xor(bs, d);
                if (ov > bvv || (ov == bvv && oi < bi)) { bvv = ov; bi = oi; bs = os; }
            }
            wk[it] = bs; ik[it] = bi; wsum += bs;
#pragma unroll
            for (int jq = 0; jq < 4; ++jq)
                if (bi == lane * 4 + jq) s[jq] = -FLT_MAX;
        }
        const float den = wsum + 1e-20f;
        if (lane == 0) {
#pragma unroll
            for (int q = 0; q < 8; ++q) {
                out[(size_t)tok * 8 + q] = wk[q] / den * 2.5f;
                out[(size_t)TDIM * 8 + (size_t)tok * 8 + q] = (float)ik[q];
            }
        }
    }
}

extern "C" void kernel_launch(void* const* d_in, const int* in_sizes, int n_in,
                              void* d_out, int out_size, void* d_ws, size_t ws_size,
                              hipStream_t stream)
{
    (void)in_sizes; (void)n_in; (void)out_size;
    const float* x    = (const float*)d_in[0];
    const float* kern = (const float*)d_in[1];
    const float* bias = (const float*)d_in[2];
    float* out = (float*)d_out;

    const size_t packedBytes = (size_t)2 * 8 * KT * 2 * 512 * 2;   // 7.34 MB
    int splitK = 4;
    while (splitK > 1 &&
           (size_t)splitK * TDIM * EDIM * 4 + packedBytes > ws_size)
        splitK >>= 1;

    float* P = (float*)d_ws;
    _Float16* Bp = (_Float16*)((char*)d_ws + (size_t)splitK * TDIM * EDIM * 4);

    convert_w<<<dim3(DDIM / 64, EDIM / 64), 256, 0, stream>>>(kern, Bp);
    gemm_mfma<<<(TDIM / 64) * splitK, 256, 0, stream>>>(
        x, Bp, P, splitK, DDIM / splitK);
    route_kernel<<<TDIM / 32, 256, 0, stream>>>(P, bias, out, splitK);
}